// Round 1
// baseline (5671.923 us; speedup 1.0000x reference)
//
#include <hip/hip_runtime.h>

#define BB 128   // batch
#define SS 128   // seq
#define EE 256   // enc dim
#define DD 256   // lstm hidden
#define OO 64    // out dim

// bf16 weight buffer layout (ushort offsets) inside d_out scratch
#define W1_OFF   0         // 768*256   = 196608 (rows: Wh|Wc|We)
#define WHH_OFF  196608    // 256*1024  = 262144
#define WIH_OFF  458752    // 64*1024   = 65536
#define FCW_OFF  524288    // 320*64    = 20480
#define WTOTAL   544768

__device__ __forceinline__ float fsig(float x) { return 1.0f / (1.0f + __expf(-x)); }
__device__ __forceinline__ float ftanh(float x) {
    float t = __expf(-2.0f * fabsf(x));
    float r = (1.0f - t) / (1.0f + t);
    return copysignf(r, x);
}
// swizzle within 32-float groups (rotation by 4*(group)): conflict-free strided access
__device__ __forceinline__ int SWZ(int e) { return (e & ~31) | ((e + 4 * (e >> 5)) & 31); }
__device__ __forceinline__ float bflo(unsigned int u) { return __uint_as_float(u << 16); }
__device__ __forceinline__ float bfhi(unsigned int u) { return __uint_as_float(u & 0xffff0000u); }

// fp32 -> bf16 (RNE) weight conversion, runs every launch (graph-safe, same work)
__global__ __launch_bounds__(256) void conv_kernel(
    const float* __restrict__ W1, const float* __restrict__ Whh,
    const float* __restrict__ Wih, const float* __restrict__ fcW,
    unsigned short* __restrict__ out)
{
    const int idx = blockIdx.x * 256 + threadIdx.x;
    float f;
    if      (idx < WHH_OFF)  f = W1[idx];
    else if (idx < WIH_OFF)  f = Whh[idx - WHH_OFF];
    else if (idx < FCW_OFF)  f = Wih[idx - WIH_OFF];
    else if (idx < WTOTAL)   f = fcW[idx - FCW_OFF];
    else return;
    unsigned int u = __float_as_uint(f);
    u = (u + 0x7fffu + ((u >> 16) & 1u)) >> 16;
    out[idx] = (unsigned short)u;
}

// One block (1024 thr, 16 waves) per batch row; whole scan block-local.
// inp slice lives in LDS (fp32, rows padded to 260 floats for bank spread).
__global__ __launch_bounds__(1024, 4) void scan_kernel(
    const float* __restrict__ inp,   // B,S,E
    const float* __restrict__ yhist, // B,S,OO
    const float* __restrict__ h0, const float* __restrict__ c0,
    const float* __restrict__ W1f,   // fp32 W1 (only We rows used here, init)
    const float* __restrict__ b1, const float* __restrict__ w2, const float* __restrict__ b2,
    const float* __restrict__ bih, const float* __restrict__ bhh,
    const float* __restrict__ fcb,
    const unsigned short* __restrict__ wbf,  // bf16 weights (see *_OFF)
    float* __restrict__ hctxT)       // ws: [512][128] (0..255 h, 256..511 ctx)
{
    __shared__ float sh_inp[SS * 260];     // 133120 B  (row stride 260 -> banks spread by 4)
    __shared__ float red[5 * 1024];        // 20480 B   shared partial buffer + gates row
    __shared__ float sh_h[DD], sh_c[DD];   // 2048
    __shared__ float sh_hc[EE];            // 1024 (SWZ'd)
    __shared__ float sh_w2[EE];            // 1024 (SWZ'd)
    __shared__ float sh_raw[SS];           // 512  exp(scores)
    __shared__ float sh_ctx[EE];           // 1024
    __shared__ float sh_y[OO], sh_yt[OO];  // 512
    __shared__ float sh_misc[1];
    // total static LDS = 159,748 B (< 163,840)

    const int b = blockIdx.x, t = threadIdx.x;
    const float* inp_b = inp + (size_t)b * SS * EE;
    const unsigned short* W1bf  = wbf + W1_OFF;
    const unsigned short* Whhbf = wbf + WHH_OFF;
    const unsigned short* Wihbf = wbf + WIH_OFF;
    const unsigned short* fcWbf = wbf + FCW_OFF;
    const float b2v = b2[0];

    // role constants
    const int c0_1 = (t & 63) * 4,  kg1 = t >> 6;   // P1 : 16 kgroups x 32k, 4 cols (uint2)
    const int c0_2 = (t & 255) * 4, kg2 = t >> 8;   // P1b/P4 : 4 kgroups, 4 cols (uint2)
    const int s_own = t >> 3, a2 = t & 7, e0 = a2 * 32;  // P2 / enc_proj
    const int c0_3 = (t & 127) * 2, sg3 = t >> 7;   // P3 : 8 sgroups x 16s, 2 cols
    const int o4 = (t & 15) * 4, kc3 = t >> 4;      // P3b

    const float bs_reg  = bih[t] + bhh[t];          // folded LSTM biases (per gate col t)
    const float fcb_reg = (t < 64) ? fcb[t] : 0.f;

    // ---- stage inp -> LDS once (fp32, padded) ----
    #pragma unroll
    for (int i = 0; i < 8; ++i) {
        const int idx = i * 1024 + t;
        const int s = idx >> 6, c4 = (idx & 63) * 4;
        *(float4*)&sh_inp[s * 260 + c4] = *(const float4*)(inp_b + (size_t)idx * 4);
    }
    if (t < 256) {
        sh_h[t] = h0[b * 256 + t]; sh_c[t] = c0[b * 256 + t];
        sh_w2[SWZ(t)] = w2[t];
    }
    __syncthreads();

    // ---- enc_proj (+b1) into registers, reading inp from LDS ----
    float er[32];
    #pragma unroll
    for (int j = 0; j < 32; ++j) er[j] = 0.f;
    {
        const float* We = W1f + 512 * 256;
        for (int kc = 0; kc < 16; ++kc) {
            {   // stage We rows [kc*16,+16) x 256 -> red[0..4095]
                const int row = t >> 6, c4 = (t & 63) * 4;
                *(float4*)&red[row * 256 + c4] =
                    *(const float4*)(We + (size_t)(kc * 16 + row) * 256 + c4);
            }
            __syncthreads();
            for (int k = 0; k < 16; ++k) {
                const float xv = sh_inp[s_own * 260 + kc * 16 + k];
                #pragma unroll
                for (int j4 = 0; j4 < 8; ++j4) {
                    float4 w = *(const float4*)&red[k * 256 + e0 + j4 * 4];
                    er[j4*4+0] += xv * w.x; er[j4*4+1] += xv * w.y;
                    er[j4*4+2] += xv * w.z; er[j4*4+3] += xv * w.w;
                }
            }
            __syncthreads();
        }
        // fold b1 into er (so per-step hc-reduce doesn't need it)
        if (t < 256) red[t] = b1[t];
        __syncthreads();
        #pragma unroll
        for (int j4 = 0; j4 < 8; ++j4) {
            float4 v = *(const float4*)&red[e0 + j4 * 4];
            er[j4*4+0] += v.x; er[j4*4+1] += v.y; er[j4*4+2] += v.z; er[j4*4+3] += v.w;
        }
        __syncthreads();
    }

    for (int ts = 0; ts < SS; ++ts) {
        if (t < 64) sh_y[t] = yhist[(size_t)b * SS * OO + ts * OO + t];

        // ---- P1: hc partials [16][256] -> red rows 0..15
        {
            float a0 = 0.f, a1 = 0.f, a2v = 0.f, a3 = 0.f;
            #pragma unroll 8
            for (int k = kg1 * 32; k < kg1 * 32 + 32; ++k) {
                const float xv = (k < 256) ? sh_h[k] : sh_c[k - 256];
                uint2 w = *(const uint2*)(W1bf + (size_t)k * 256 + c0_1);
                a0  += xv * bflo(w.x); a1 += xv * bfhi(w.x);
                a2v += xv * bflo(w.y); a3 += xv * bfhi(w.y);
            }
            *(float4*)&red[kg1 * 256 + c0_1] = make_float4(a0, a1, a2v, a3);
        }
        __syncthreads();                                     // bar A
        if (t < 256) {
            float v = 0.f;
            #pragma unroll
            for (int kg = 0; kg < 16; ++kg) v += red[kg * 256 + t];
            sh_hc[SWZ(t)] = v;                               // b1 already in er
        }
        __syncthreads();                                     // bar B

        // ---- P1b (Whh, biggest stream) fused with P2 (tanh hides load latency)
        {
            float a0 = 0.f, a1 = 0.f, a2v = 0.f, a3 = 0.f;
            #pragma unroll 8
            for (int k = kg2 * 64; k < kg2 * 64 + 64; ++k) {
                const float hv = sh_h[k];
                uint2 w = *(const uint2*)(Whhbf + (size_t)k * 1024 + c0_2);
                a0  += hv * bflo(w.x); a1 += hv * bfhi(w.x);
                a2v += hv * bflo(w.y); a3 += hv * bfhi(w.y);
            }
            *(float4*)&red[kg2 * 1024 + c0_2] = make_float4(a0, a1, a2v, a3);
        }
        // ---- P2: scores from register er + swizzled hc/w2 (conflict-free)
        {
            float acc = 0.f;
            #pragma unroll
            for (int j4 = 0; j4 < 8; ++j4) {
                const int phys = e0 + ((j4 * 4 + 4 * a2) & 31);
                float4 hc4 = *(const float4*)&sh_hc[phys];
                float4 w24 = *(const float4*)&sh_w2[phys];
                acc += ftanh(er[j4*4+0] + hc4.x) * w24.x;
                acc += ftanh(er[j4*4+1] + hc4.y) * w24.y;
                acc += ftanh(er[j4*4+2] + hc4.z) * w24.z;
                acc += ftanh(er[j4*4+3] + hc4.w) * w24.w;
            }
            acc += __shfl_xor(acc, 1);
            acc += __shfl_xor(acc, 2);
            acc += __shfl_xor(acc, 4);
            if (a2 == 0) sh_raw[s_own] = __expf(acc + b2v);  // max-free: |score| <= sum|w2| ~ 10
        }
        __syncthreads();                                     // bar C

        // ---- gh reduce (into register; includes LSTM biases) + softmax denom
        float gh_reg;
        {
            float v = bs_reg;
            #pragma unroll
            for (int kg = 0; kg < 4; ++kg) v += red[kg * 1024 + t];
            gh_reg = v;
        }
        if (t < 64) {
            float v = sh_raw[t] + sh_raw[t + 64];
            #pragma unroll
            for (int m = 32; m > 0; m >>= 1) v += __shfl_xor(v, m);
            if (t == 0) sh_misc[0] = 1.0f / v;
        }
        __syncthreads();                                     // bar D

        // ---- P3: context partials [8][256] from LDS inp; prefetch Wih for P4
        uint2 wpre[16];
        #pragma unroll
        for (int i = 0; i < 16; ++i)
            wpre[i] = *(const uint2*)(Wihbf + (size_t)(kg2 * 16 + i) * 1024 + c0_2);
        {
            float ax = 0.f, ay = 0.f;
            #pragma unroll
            for (int i = 0; i < 16; ++i) {
                const int s = sg3 * 16 + i;
                const float al = sh_raw[s];
                ax += al * sh_inp[s * 260 + c0_3];
                ay += al * sh_inp[s * 260 + c0_3 + 1];
            }
            *(float2*)&red[sg3 * 256 + c0_3] = make_float2(ax, ay);
        }
        __syncthreads();                                     // bar E
        if (t < 256) {
            float v = 0.f;
            #pragma unroll
            for (int sg = 0; sg < 8; ++sg) v += red[sg * 256 + t];
            v *= sh_misc[0];
            sh_ctx[t] = v;
            if (ts == SS - 1) hctxT[(size_t)(256 + t) * 128 + b] = v;
        }
        __syncthreads();                                     // bar F

        // ---- P3b: y_tilde partials [64][64] -> red[0..4095]
        {
            float a0 = 0.f, a1 = 0.f, a2v = 0.f, a3 = 0.f;
            for (int kk = kc3 * 5; kk < kc3 * 5 + 5; ++kk) {
                const float val = (kk < 256) ? sh_ctx[kk] : sh_y[kk - 256];
                uint2 w = *(const uint2*)(fcWbf + kk * 64 + o4);
                a0  += val * bflo(w.x); a1 += val * bfhi(w.x);
                a2v += val * bflo(w.y); a3 += val * bfhi(w.y);
            }
            *(float4*)&red[kc3 * 64 + o4] = make_float4(a0, a1, a2v, a3);
        }
        __syncthreads();                                     // bar G
        if (t < 64) {
            float v = fcb_reg;
            #pragma unroll 16
            for (int kg = 0; kg < 64; ++kg) v += red[kg * 64 + t];
            sh_yt[t] = v;
        }
        __syncthreads();                                     // bar H

        // ---- P4: gate partials (Wih from prefetched regs) [4][1024]
        {
            float a0 = 0.f, a1 = 0.f, a2v = 0.f, a3 = 0.f;
            #pragma unroll
            for (int i = 0; i < 16; ++i) {
                const float yv = sh_yt[kg2 * 16 + i];
                const uint2 w = wpre[i];
                a0  += yv * bflo(w.x); a1 += yv * bfhi(w.x);
                a2v += yv * bflo(w.y); a3 += yv * bfhi(w.y);
            }
            *(float4*)&red[kg2 * 1024 + c0_2] = make_float4(a0, a1, a2v, a3);
        }
        __syncthreads();                                     // bar I
        {
            float g = gh_reg;
            #pragma unroll
            for (int kg = 0; kg < 4; ++kg) g += red[kg * 1024 + t];
            red[4096 + t] = g;   // gates[1024] (disjoint from partial rows)
        }
        __syncthreads();                                     // bar J
        if (t < 256) {
            const float gi = red[4096 + t], gf = red[4096 + 256 + t];
            const float gg = red[4096 + 512 + t], go = red[4096 + 768 + t];
            const float cn = fsig(gf) * sh_c[t] + fsig(gi) * ftanh(gg);
            sh_c[t] = cn;
            const float hn = fsig(go) * ftanh(cn);
            sh_h[t] = hn;
            if (ts == SS - 1) hctxT[(size_t)t * 128 + b] = hn;
        }
        __syncthreads();                                     // bar K
    }
}

// out(128 x 8192) = A(128x512, stored transposed AT[512][128]) @ W(512x8192) + bias
__global__ __launch_bounds__(256) void out_gemm(
    const float* __restrict__ AT, const float* __restrict__ W,
    const float* __restrict__ bias, float* __restrict__ out)
{
    __shared__ float Ab[64 * 132];  // [k][m]
    __shared__ float Bb[64 * 32];   // [k][n]
    const int t = threadIdx.x;
    const int nt = blockIdx.x * 32;
    const int n4 = (t & 7) * 4;
    const int m4 = (t >> 3) * 4;
    float acc[4][4];
    #pragma unroll
    for (int i = 0; i < 4; ++i)
        #pragma unroll
        for (int jj = 0; jj < 4; ++jj) acc[i][jj] = 0.f;

    for (int kc = 0; kc < 8; ++kc) {
        #pragma unroll
        for (int i = 0; i < 8; ++i) {
            const int flat4 = i * 256 + t;
            const int row = flat4 >> 5, mm4 = (flat4 & 31) * 4;
            float4 v = *(const float4*)(AT + (size_t)(kc * 64 + row) * 128 + mm4);
            *(float4*)&Ab[row * 132 + mm4] = v;
        }
        #pragma unroll
        for (int i = 0; i < 2; ++i) {
            const int fl = t + i * 256;
            const int k = fl >> 3, nn4 = (fl & 7) * 4;
            *(float4*)&Bb[k * 32 + nn4] =
                *(const float4*)(W + (size_t)(kc * 64 + k) * 8192 + nt + nn4);
        }
        __syncthreads();
        for (int k = 0; k < 64; ++k) {
            const float4 bv = *(const float4*)&Bb[k * 32 + n4];
            const float4 av = *(const float4*)&Ab[k * 132 + m4];
            acc[0][0] += av.x * bv.x; acc[0][1] += av.x * bv.y; acc[0][2] += av.x * bv.z; acc[0][3] += av.x * bv.w;
            acc[1][0] += av.y * bv.x; acc[1][1] += av.y * bv.y; acc[1][2] += av.y * bv.z; acc[1][3] += av.y * bv.w;
            acc[2][0] += av.z * bv.x; acc[2][1] += av.z * bv.y; acc[2][2] += av.z * bv.z; acc[2][3] += av.z * bv.w;
            acc[3][0] += av.w * bv.x; acc[3][1] += av.w * bv.y; acc[3][2] += av.w * bv.z; acc[3][3] += av.w * bv.w;
        }
        __syncthreads();
    }
    const float4 bb = *(const float4*)(bias + nt + n4);
    #pragma unroll
    for (int i = 0; i < 4; ++i) {
        float4 r;
        r.x = acc[i][0] + bb.x; r.y = acc[i][1] + bb.y;
        r.z = acc[i][2] + bb.z; r.w = acc[i][3] + bb.w;
        *(float4*)(out + (size_t)(m4 + i) * 8192 + nt + n4) = r;
    }
}

extern "C" void kernel_launch(void* const* d_in, const int* in_sizes, int n_in,
                              void* d_out, int out_size, void* d_ws, size_t ws_size,
                              hipStream_t stream) {
    const float* inp = (const float*)d_in[0];
    const float* yh  = (const float*)d_in[1];
    const float* h0  = (const float*)d_in[2];
    const float* c0  = (const float*)d_in[3];
    const float* W1  = (const float*)d_in[4];
    const float* b1  = (const float*)d_in[5];
    const float* w2  = (const float*)d_in[6];
    const float* b2  = (const float*)d_in[7];
    const float* Wih = (const float*)d_in[8];
    const float* Whh = (const float*)d_in[9];
    const float* bih = (const float*)d_in[10];
    const float* bhh = (const float*)d_in[11];
    const float* fcW = (const float*)d_in[12];
    const float* fcb = (const float*)d_in[13];
    const float* foW = (const float*)d_in[14];
    const float* fob = (const float*)d_in[15];

    float* hctxT = (float*)d_ws;                    // 256 KB (proven)
    unsigned short* wbf = (unsigned short*)d_out;   // 1.09 MB bf16 weights in d_out scratch
                                                    // (overwritten by out_gemm at the end)

    conv_kernel<<<dim3((WTOTAL + 255) / 256), dim3(256), 0, stream>>>(W1, Whh, Wih, fcW, wbf);
    scan_kernel<<<dim3(BB), dim3(1024), 0, stream>>>(
        inp, yh, h0, c0, W1, b1, w2, b2, bih, bhh, fcb, wbf, hctxT);
    out_gemm<<<dim3(8192 / 32), dim3(256), 0, stream>>>(hctxT, foW, fob, (float*)d_out);
}

// Round 2
// 5482.539 us; speedup vs baseline: 1.0345x; 1.0345x over previous
//
#include <hip/hip_runtime.h>

#define BB 128   // batch
#define SS 128   // seq
#define EE 256   // enc dim
#define DD 256   // lstm hidden
#define OO 64    // out dim

// bf16 weight buffer layout (ushort offsets) inside d_out scratch
#define W1_OFF   0         // 768*256   = 196608 (rows: Wh|Wc|We)
#define WHH_OFF  196608    // 256*1024  = 262144
#define WIH_OFF  458752    // 64*1024   = 65536
#define FCW_OFF  524288    // 320*64    = 20480
#define WTOTAL   544768

__device__ __forceinline__ float fsig(float x) { return 1.0f / (1.0f + __expf(-x)); }
__device__ __forceinline__ float ftanh(float x) {
    float t = __expf(-2.0f * fabsf(x));
    float r = (1.0f - t) / (1.0f + t);
    return copysignf(r, x);
}
// swizzle within 32-float groups (rotation by 4*(group)): conflict-free strided access
__device__ __forceinline__ int SWZ(int e) { return (e & ~31) | ((e + 4 * (e >> 5)) & 31); }
__device__ __forceinline__ float bflo(unsigned int u) { return __uint_as_float(u << 16); }
__device__ __forceinline__ float bfhi(unsigned int u) { return __uint_as_float(u & 0xffff0000u); }

__device__ __forceinline__ void fma8(const uint4 w, const float xv, float* acc) {
    acc[0] += xv * bflo(w.x); acc[1] += xv * bfhi(w.x);
    acc[2] += xv * bflo(w.y); acc[3] += xv * bfhi(w.y);
    acc[4] += xv * bflo(w.z); acc[5] += xv * bfhi(w.z);
    acc[6] += xv * bflo(w.w); acc[7] += xv * bfhi(w.w);
}

// fp32 -> bf16 (RNE) weight conversion, runs every launch (graph-safe, same work)
__global__ __launch_bounds__(256) void conv_kernel(
    const float* __restrict__ W1, const float* __restrict__ Whh,
    const float* __restrict__ Wih, const float* __restrict__ fcW,
    unsigned short* __restrict__ out)
{
    const int idx = blockIdx.x * 256 + threadIdx.x;
    float f;
    if      (idx < WHH_OFF)  f = W1[idx];
    else if (idx < WIH_OFF)  f = Whh[idx - WHH_OFF];
    else if (idx < FCW_OFF)  f = Wih[idx - WIH_OFF];
    else if (idx < WTOTAL)   f = fcW[idx - FCW_OFF];
    else return;
    unsigned int u = __float_as_uint(f);
    u = (u + 0x7fffu + ((u >> 16) & 1u)) >> 16;
    out[idx] = (unsigned short)u;
}

// One block (1024 thr, 16 waves) per batch row; whole scan block-local.
// inp fp32 in LDS; Wih+fcW register-resident; P1b/P4 reduced via shfl (no red2).
__global__ __launch_bounds__(1024, 4) void scan_kernel(
    const float* __restrict__ inp,   // B,S,E
    const float* __restrict__ yhist, // B,S,OO
    const float* __restrict__ h0, const float* __restrict__ c0,
    const float* __restrict__ W1f,   // fp32 W1 (only We rows used here, init)
    const float* __restrict__ b1, const float* __restrict__ w2, const float* __restrict__ b2,
    const float* __restrict__ bih, const float* __restrict__ bhh,
    const float* __restrict__ fcb,
    const unsigned short* __restrict__ wbf,  // bf16 weights (see *_OFF)
    float* __restrict__ hctxT)       // ws: [512][128] (0..255 h, 256..511 ctx)
{
    __shared__ float sh_inp[SS * 260];     // 133120 B (stride 260: float4-aligned, bank-spread)
    __shared__ float red1[16 * 256];       // 16384 B  partials (P1 / P3 / gates / init We)
    __shared__ float sh_bs[1024];          // 4096     bih+bhh
    __shared__ float sh_h[DD], sh_c[DD];   // 2048
    __shared__ float sh_hc[EE];            // 1024 (SWZ'd)
    __shared__ float sh_w2[EE];            // 1024 (SWZ'd)
    __shared__ float sh_raw[SS];           // 512  exp(scores)
    __shared__ float sh_ctx[EE];           // 1024
    __shared__ float sh_y[OO], sh_yt[OO];  // 512
    __shared__ float sh_misc[1];
    // total ~159.8 KB

    const int b = blockIdx.x, t = threadIdx.x;
    const float* inp_b = inp + (size_t)b * SS * EE;
    const unsigned short* W1bf  = wbf + W1_OFF;
    const unsigned short* Whhbf = wbf + WHH_OFF;
    const unsigned short* Wihbf = wbf + WIH_OFF;
    const unsigned short* fcWbf = wbf + FCW_OFF;
    const float b2v = b2[0];
    const int lane = t & 63;

    // role constants
    const int e8 = (t & 31) * 8, kc1 = t >> 5;        // P1: 32 kg x 16k, 8 cols (uint4)
    const int cg2 = t >> 3, kg2 = t & 7;              // P1b/P4: 128 cg x 8 cols; kg in-wave
    const int s_own = t >> 3, a2 = t & 7, e0 = a2 * 32;  // P2 / enc_proj
    const int e4 = (t & 63) * 4, sg3 = t >> 6;        // P3: 16 sg x 8 s, 4 cols
    const int kf = (t & 63) * 5, cf = (t >> 6) * 4;   // P3b: 64 kg x 5k, 4 cols (wave = cg)

    // ---- stage inp -> LDS once (fp32, padded) ----
    #pragma unroll
    for (int i = 0; i < 8; ++i) {
        const int idx = i * 1024 + t;
        const int s = idx >> 6, c4 = (idx & 63) * 4;
        *(float4*)&sh_inp[s * 260 + c4] = *(const float4*)(inp_b + (size_t)idx * 4);
    }
    if (t < 256) {
        sh_h[t] = h0[b * 256 + t]; sh_c[t] = c0[b * 256 + t];
        sh_w2[SWZ(t)] = w2[t];
    }
    sh_bs[t] = bih[t] + bhh[t];

    // ---- register-resident Wih (8 rows x 8 cols per thread) and fcW (5 x 4) ----
    uint4 wih_r[8];
    #pragma unroll
    for (int i = 0; i < 8; ++i)
        wih_r[i] = *(const uint4*)(Wihbf + (size_t)(kg2 * 8 + i) * 1024 + cg2 * 8);
    uint2 fcw_r[5];
    #pragma unroll
    for (int i = 0; i < 5; ++i)
        fcw_r[i] = *(const uint2*)(fcWbf + (kf + i) * 64 + cf);
    __syncthreads();

    // ---- enc_proj (+b1) into registers, reading inp from LDS ----
    float er[32];
    #pragma unroll
    for (int j = 0; j < 32; ++j) er[j] = 0.f;
    {
        const float* We = W1f + 512 * 256;
        for (int kc = 0; kc < 16; ++kc) {
            {   // stage We rows [kc*16,+16) x 256 -> red1
                const int row = t >> 6, c4 = (t & 63) * 4;
                *(float4*)&red1[row * 256 + c4] =
                    *(const float4*)(We + (size_t)(kc * 16 + row) * 256 + c4);
            }
            __syncthreads();
            for (int k = 0; k < 16; ++k) {
                const float xv = sh_inp[s_own * 260 + kc * 16 + k];
                #pragma unroll
                for (int j4 = 0; j4 < 8; ++j4) {
                    float4 w = *(const float4*)&red1[k * 256 + e0 + j4 * 4];
                    er[j4*4+0] += xv * w.x; er[j4*4+1] += xv * w.y;
                    er[j4*4+2] += xv * w.z; er[j4*4+3] += xv * w.w;
                }
            }
            __syncthreads();
        }
        // fold b1 into er
        if (t < 256) red1[t] = b1[t];
        __syncthreads();
        #pragma unroll
        for (int j4 = 0; j4 < 8; ++j4) {
            float4 v = *(const float4*)&red1[e0 + j4 * 4];
            er[j4*4+0] += v.x; er[j4*4+1] += v.y; er[j4*4+2] += v.z; er[j4*4+3] += v.w;
        }
        __syncthreads();
    }

    for (int ts = 0; ts < SS; ++ts) {
        if (t < 64) sh_y[t] = yhist[(size_t)b * SS * OO + ts * OO + t];

        // ---- P1: hc partials; shfl-pair kc -> [16][256] in red1
        {
            float acc[8];
            #pragma unroll
            for (int r = 0; r < 8; ++r) acc[r] = 0.f;
            #pragma unroll 4
            for (int k = kc1 * 16; k < kc1 * 16 + 16; ++k) {
                const float xv = (k < 256) ? sh_h[k] : sh_c[k - 256];
                uint4 w = *(const uint4*)(W1bf + (size_t)k * 256 + e8);
                fma8(w, xv, acc);
            }
            #pragma unroll
            for (int r = 0; r < 8; ++r) acc[r] += __shfl_xor(acc[r], 32);
            if ((t & 32) == 0) {
                *(float4*)&red1[(kc1 >> 1) * 256 + e8]     = make_float4(acc[0], acc[1], acc[2], acc[3]);
                *(float4*)&red1[(kc1 >> 1) * 256 + e8 + 4] = make_float4(acc[4], acc[5], acc[6], acc[7]);
            }
        }
        __syncthreads();                                     // bar A
        if (t < 256) {
            float v = 0.f;
            #pragma unroll
            for (int r = 0; r < 16; ++r) v += red1[r * 256 + t];
            sh_hc[SWZ(t)] = v;                               // b1 already in er
        }
        __syncthreads();                                     // bar B

        // ---- P1b (Whh, uint4, accumulate in regs; shfl-reduce deferred to P4)
        float g[8];
        #pragma unroll
        for (int r = 0; r < 8; ++r) g[r] = 0.f;
        #pragma unroll 8
        for (int i = 0; i < 32; ++i) {
            const int k = kg2 * 32 + ((i + 4 * kg2) & 31);   // rotation: bank-spread sh_h read
            const float hv = sh_h[k];
            uint4 w = *(const uint4*)(Whhbf + (size_t)k * 1024 + cg2 * 8);
            fma8(w, hv, g);
        }
        // ---- P2: scores (tanh hides Whh load latency)
        {
            float sacc = 0.f;
            #pragma unroll
            for (int j4 = 0; j4 < 8; ++j4) {
                const int phys = e0 + ((j4 * 4 + 4 * a2) & 31);
                float4 hc4 = *(const float4*)&sh_hc[phys];
                float4 w24 = *(const float4*)&sh_w2[phys];
                sacc += ftanh(er[j4*4+0] + hc4.x) * w24.x;
                sacc += ftanh(er[j4*4+1] + hc4.y) * w24.y;
                sacc += ftanh(er[j4*4+2] + hc4.z) * w24.z;
                sacc += ftanh(er[j4*4+3] + hc4.w) * w24.w;
            }
            sacc += __shfl_xor(sacc, 1);
            sacc += __shfl_xor(sacc, 2);
            sacc += __shfl_xor(sacc, 4);
            if (a2 == 0) sh_raw[s_own] = __expf(sacc + b2v);  // max-free: |score| <= sum|w2| ~ 10
        }
        __syncthreads();                                     // bar C

        // ---- P3: context partials [16][256] from LDS inp; denom folded in
        {
            float ax = 0.f, ay = 0.f, az = 0.f, aw = 0.f;
            #pragma unroll
            for (int i = 0; i < 8; ++i) {
                const int s = sg3 * 8 + i;
                const float al = sh_raw[s];
                float4 iv = *(const float4*)&sh_inp[s * 260 + e4];
                ax += al * iv.x; ay += al * iv.y; az += al * iv.z; aw += al * iv.w;
            }
            *(float4*)&red1[sg3 * 256 + e4] = make_float4(ax, ay, az, aw);
        }
        if (t < 64) {
            float v = sh_raw[t] + sh_raw[t + 64];
            #pragma unroll
            for (int m = 32; m > 0; m >>= 1) v += __shfl_xor(v, m);
            if (t == 0) sh_misc[0] = 1.0f / v;
        }
        __syncthreads();                                     // bar E
        if (t < 256) {
            float v = 0.f;
            #pragma unroll
            for (int r = 0; r < 16; ++r) v += red1[r * 256 + t];
            v *= sh_misc[0];
            sh_ctx[t] = v;
            if (ts == SS - 1) hctxT[(size_t)(256 + t) * 128 + b] = v;
        }
        __syncthreads();                                     // bar F

        // ---- P3b: y_tilde from register fcW; full-wave shfl reduce (wave = 4 out cols)
        {
            float a0 = 0.f, a1 = 0.f, a2v = 0.f, a3 = 0.f;
            #pragma unroll
            for (int i = 0; i < 5; ++i) {
                const int k = kf + i;
                const float val = (k < 256) ? sh_ctx[k] : sh_y[k - 256];
                const uint2 w = fcw_r[i];
                a0  += val * bflo(w.x); a1 += val * bfhi(w.x);
                a2v += val * bflo(w.y); a3 += val * bfhi(w.y);
            }
            #pragma unroll
            for (int m = 1; m < 64; m <<= 1) {
                a0  += __shfl_xor(a0, m);  a1 += __shfl_xor(a1, m);
                a2v += __shfl_xor(a2v, m); a3 += __shfl_xor(a3, m);
            }
            if (lane == 0) {
                float4 r; r.x = a0 + fcb[cf]; r.y = a1 + fcb[cf + 1];
                r.z = a2v + fcb[cf + 2]; r.w = a3 + fcb[cf + 3];
                *(float4*)&sh_yt[cf] = r;
            }
        }
        __syncthreads();                                     // bar H

        // ---- P4: gate contribution from register Wih; in-wave kg reduce; write gates
        #pragma unroll
        for (int i = 0; i < 8; ++i) {
            const float yv = sh_yt[kg2 * 8 + i];
            fma8(wih_r[i], yv, g);
        }
        #pragma unroll
        for (int r = 0; r < 8; ++r) {
            g[r] += __shfl_xor(g[r], 1);
            g[r] += __shfl_xor(g[r], 2);
            g[r] += __shfl_xor(g[r], 4);
        }
        if (kg2 == 0) {
            *(float4*)&red1[cg2 * 8]     = make_float4(g[0], g[1], g[2], g[3]);
            *(float4*)&red1[cg2 * 8 + 4] = make_float4(g[4], g[5], g[6], g[7]);
        }
        __syncthreads();                                     // bar I
        if (t < 256) {
            const float gi = red1[t]       + sh_bs[t];
            const float gf = red1[256 + t] + sh_bs[256 + t];
            const float gg = red1[512 + t] + sh_bs[512 + t];
            const float go = red1[768 + t] + sh_bs[768 + t];
            const float cn = fsig(gf) * sh_c[t] + fsig(gi) * ftanh(gg);
            sh_c[t] = cn;
            const float hn = fsig(go) * ftanh(cn);
            sh_h[t] = hn;
            if (ts == SS - 1) hctxT[(size_t)t * 128 + b] = hn;
        }
        __syncthreads();                                     // bar J
    }
}

// out(128 x 8192) = A(128x512, stored transposed AT[512][128]) @ W(512x8192) + bias
__global__ __launch_bounds__(256) void out_gemm(
    const float* __restrict__ AT, const float* __restrict__ W,
    const float* __restrict__ bias, float* __restrict__ out)
{
    __shared__ float Ab[64 * 132];  // [k][m]
    __shared__ float Bb[64 * 32];   // [k][n]
    const int t = threadIdx.x;
    const int nt = blockIdx.x * 32;
    const int n4 = (t & 7) * 4;
    const int m4 = (t >> 3) * 4;
    float acc[4][4];
    #pragma unroll
    for (int i = 0; i < 4; ++i)
        #pragma unroll
        for (int jj = 0; jj < 4; ++jj) acc[i][jj] = 0.f;

    for (int kc = 0; kc < 8; ++kc) {
        #pragma unroll
        for (int i = 0; i < 8; ++i) {
            const int flat4 = i * 256 + t;
            const int row = flat4 >> 5, mm4 = (flat4 & 31) * 4;
            float4 v = *(const float4*)(AT + (size_t)(kc * 64 + row) * 128 + mm4);
            *(float4*)&Ab[row * 132 + mm4] = v;
        }
        #pragma unroll
        for (int i = 0; i < 2; ++i) {
            const int fl = t + i * 256;
            const int k = fl >> 3, nn4 = (fl & 7) * 4;
            *(float4*)&Bb[k * 32 + nn4] =
                *(const float4*)(W + (size_t)(kc * 64 + k) * 8192 + nt + nn4);
        }
        __syncthreads();
        for (int k = 0; k < 64; ++k) {
            const float4 bv = *(const float4*)&Bb[k * 32 + n4];
            const float4 av = *(const float4*)&Ab[k * 132 + m4];
            acc[0][0] += av.x * bv.x; acc[0][1] += av.x * bv.y; acc[0][2] += av.x * bv.z; acc[0][3] += av.x * bv.w;
            acc[1][0] += av.y * bv.x; acc[1][1] += av.y * bv.y; acc[1][2] += av.y * bv.z; acc[1][3] += av.y * bv.w;
            acc[2][0] += av.z * bv.x; acc[2][1] += av.z * bv.y; acc[2][2] += av.z * bv.z; acc[2][3] += av.z * bv.w;
            acc[3][0] += av.w * bv.x; acc[3][1] += av.w * bv.y; acc[3][2] += av.w * bv.z; acc[3][3] += av.w * bv.w;
        }
        __syncthreads();
    }
    const float4 bb = *(const float4*)(bias + nt + n4);
    #pragma unroll
    for (int i = 0; i < 4; ++i) {
        float4 r;
        r.x = acc[i][0] + bb.x; r.y = acc[i][1] + bb.y;
        r.z = acc[i][2] + bb.z; r.w = acc[i][3] + bb.w;
        *(float4*)(out + (size_t)(m4 + i) * 8192 + nt + n4) = r;
    }
}

extern "C" void kernel_launch(void* const* d_in, const int* in_sizes, int n_in,
                              void* d_out, int out_size, void* d_ws, size_t ws_size,
                              hipStream_t stream) {
    const float* inp = (const float*)d_in[0];
    const float* yh  = (const float*)d_in[1];
    const float* h0  = (const float*)d_in[2];
    const float* c0  = (const float*)d_in[3];
    const float* W1  = (const float*)d_in[4];
    const float* b1  = (const float*)d_in[5];
    const float* w2  = (const float*)d_in[6];
    const float* b2  = (const float*)d_in[7];
    const float* Wih = (const float*)d_in[8];
    const float* Whh = (const float*)d_in[9];
    const float* bih = (const float*)d_in[10];
    const float* bhh = (const float*)d_in[11];
    const float* fcW = (const float*)d_in[12];
    const float* fcb = (const float*)d_in[13];
    const float* foW = (const float*)d_in[14];
    const float* fob = (const float*)d_in[15];

    float* hctxT = (float*)d_ws;                    // 256 KB (proven)
    unsigned short* wbf = (unsigned short*)d_out;   // 1.09 MB bf16 weights in d_out scratch
                                                    // (overwritten by out_gemm at the end)

    conv_kernel<<<dim3((WTOTAL + 255) / 256), dim3(256), 0, stream>>>(W1, Whh, Wih, fcW, wbf);
    scan_kernel<<<dim3(BB), dim3(1024), 0, stream>>>(
        inp, yh, h0, c0, W1, b1, w2, b2, bih, bhh, fcb, wbf, hctxT);
    out_gemm<<<dim3(8192 / 32), dim3(256), 0, stream>>>(hctxT, foW, fob, (float*)d_out);
}